// Round 4
// baseline (138.229 us; speedup 1.0000x reference)
//
#include <hip/hip_runtime.h>

// DifferentiableFK: serial 63-body hinge chain, B=131072.
// Evidence trail: R1 (bf16 input reads) -> NaN => inputs fp32.
//                 R2==R3 bitwise (detector chose fp32 everywhere) => all inputs fp32.
//                 R2/R3 absmax 5.92 == fp32-read-of-packed-bf16-stream artifact
//                 => OUTPUT buffer is fp32, not bf16 (reference returns float32).
// R4: fp32 in / fp32 math / fp32 out. One thread per batch element; chain
// state in registers; per-hinge constants precomputed once into d_ws.

#define NBODY  63
#define NHINGE 61
#define NSITES 16
#define QDIM   68   // 7 + NHINGE

typedef unsigned int u32;

// ws float-index layout (setup kernel writes, main kernel reads)
#define HC_OFF   0                        // [61][16]: u.wxyz, v.wxyz, a.xyz+pad, j.xyz+pad
#define SP_OFF   (NHINGE * 16)            // 976: [16][4] site_pos
#define MASK_OFF (SP_OFF + NSITES * 4)    // 1040: int[63] per-body site bitmask
#define BM_OFF   (MASK_OFF + 64)          // 1104: 2 x u32 body bitmask

__global__ void fk_setup(const float* __restrict__ body_pos, const float* __restrict__ body_quat,
                         const float* __restrict__ hinge_axis, const float* __restrict__ jnt_pos,
                         const float* __restrict__ site_pos, const int* __restrict__ site_body,
                         float* __restrict__ ws)
{
    int tid = threadIdx.x;
    if (tid < NHINGE) {
        int h = tid, bid = h + 2;
        float uw = body_quat[bid*4+0], ux = body_quat[bid*4+1];
        float uy = body_quat[bid*4+2], uz = body_quat[bid*4+3];
        float ax = hinge_axis[h*3+0], ay = hinge_axis[h*3+1], az = hinge_axis[h*3+2];
        float jx = jnt_pos[h*3+0],   jy = jnt_pos[h*3+1],   jz = jnt_pos[h*3+2];
        float bx = body_pos[bid*3+0], by = body_pos[bid*3+1], bz = body_pos[bid*3+2];
        float* o = ws + HC_OFF + h * 16;
        o[0] = uw; o[1] = ux; o[2] = uy; o[3] = uz;
        // v = body_quat (x) (0, axis)  -> local = cos*u + sin*v
        o[4] = -(ux * ax + uy * ay + uz * az);
        o[5] =  uw * ax + uy * az - uz * ay;
        o[6] =  uw * ay - ux * az + uz * ax;
        o[7] =  uw * az + ux * ay - uy * ax;
        o[8] = bx + jx; o[9] = by + jy; o[10] = bz + jz; o[11] = 0.f;
        o[12] = jx; o[13] = jy; o[14] = jz; o[15] = 0.f;
    }
    if (tid < NSITES) {
        float* o = ws + SP_OFF + tid * 4;
        o[0] = site_pos[tid*3+0];
        o[1] = site_pos[tid*3+1];
        o[2] = site_pos[tid*3+2];
        o[3] = 0.f;
    }
    if (tid == 0) {
        int* im = (int*)(ws + MASK_OFF);
        unsigned long long bm = 0ull;
        for (int b = 0; b < NBODY; b++) {
            int m = 0;
            for (int s = 0; s < NSITES; s++)
                if (site_body[s] == b) m |= (1 << s);
            im[b] = m;
            if (m) bm |= (1ull << b);
        }
        u32* pbm = (u32*)(ws + BM_OFF);
        pbm[0] = (u32)bm; pbm[1] = (u32)(bm >> 32);
    }
}

__global__ __launch_bounds__(256, 2)
void fk_main(const float* __restrict__ qpos, const float* __restrict__ ws,
             float* __restrict__ out, int nb)
{
    int t = blockIdx.x * 256 + threadIdx.x;
    if (t >= nb) return;

    // ---- load full qpos row: 68 floats = 272 B = 17 x float4 (16B-aligned) ----
    float f[QDIM];
    const float4* q4 = reinterpret_cast<const float4*>(qpos) + (size_t)t * 17;
#pragma unroll
    for (int i = 0; i < 17; i++) {
        float4 v = q4[i];
        f[4*i+0] = v.x; f[4*i+1] = v.y; f[4*i+2] = v.z; f[4*i+3] = v.w;
    }

    const u32* pbm = (const u32*)(ws + BM_OFF);
    unsigned long long bodymask = ((unsigned long long)pbm[1] << 32) | (unsigned long long)pbm[0];
    const int* im = (const int*)(ws + MASK_OFF);

    // ---- body 1: free joint ----
    float wpx = f[0], wpy = f[1], wpz = f[2];
    float qw = f[3], qx = f[4], qy = f[5], qz = f[6];
    float inv = rsqrtf(qw * qw + qx * qx + qy * qy + qz * qz);
    qw *= inv; qx *= inv; qy *= inv; qz *= inv;

    auto emit = [&](int bid) {
        int m = im[bid];          // wave-uniform
        while (m) {
            int s = __ffs(m) - 1; m &= m - 1;
            const float* sp = ws + SP_OFF + s * 4;
            float vx = sp[0], vy = sp[1], vz = sp[2];
            float tx = 2.f * (qy * vz - qz * vy);
            float ty = 2.f * (qz * vx - qx * vz);
            float tz = 2.f * (qx * vy - qy * vx);
            float ox = wpx + vx + qw * tx + (qy * tz - qz * ty);
            float oy = wpy + vy + qw * ty + (qz * tx - qx * tz);
            float oz = wpz + vz + qw * tz + (qx * ty - qy * tx);
            size_t base = ((size_t)t * NSITES + s) * 3;
            out[base + 0] = ox;
            out[base + 1] = oy;
            out[base + 2] = oz;
        }
    };

    if (bodymask & 2ull) emit(1);

    // ---- serial hinge chain, fully unrolled ----
#pragma unroll
    for (int h = 0; h < NHINGE; h++) {
        const int bid = h + 2;
        const float* c = ws + HC_OFF + h * 16;   // uniform, static offsets
        float ang = 0.5f * f[7 + h];
        float sn, cs;
        __sincosf(ang, &sn, &cs);
        // local = cs*u + sn*v
        float lw = cs * c[0] + sn * c[4];
        float lx = cs * c[1] + sn * c[5];
        float ly = cs * c[2] + sn * c[6];
        float lz = cs * c[3] + sn * c[7];
        // anchor = wp + qrot(wq, body_pos + jnt_pos)
        float ax = c[8], ay = c[9], az = c[10];
        float tx = 2.f * (qy * az - qz * ay);
        float ty = 2.f * (qz * ax - qx * az);
        float tz = 2.f * (qx * ay - qy * ax);
        float anx = wpx + ax + qw * tx + (qy * tz - qz * ty);
        float any_ = wpy + ay + qw * ty + (qz * tx - qx * tz);
        float anz = wpz + az + qw * tz + (qx * ty - qy * tx);
        // nq = qmul(wq, local)
        float nw = qw * lw - qx * lx - qy * ly - qz * lz;
        float nx = qw * lx + qx * lw + qy * lz - qz * ly;
        float ny = qw * ly - qx * lz + qy * lw + qz * lx;
        float nz = qw * lz + qx * ly - qy * lx + qz * lw;
        // wp = anchor - qrot(nq, jnt_pos)
        float jx = c[12], jy = c[13], jz = c[14];
        float t2x = 2.f * (ny * jz - nz * jy);
        float t2y = 2.f * (nz * jx - nx * jz);
        float t2z = 2.f * (nx * jy - ny * jx);
        wpx = anx - (jx + nw * t2x + (ny * t2z - nz * t2y));
        wpy = any_ - (jy + nw * t2y + (nz * t2x - nx * t2z));
        wpz = anz - (jz + nw * t2z + (nx * t2y - ny * t2x));
        qw = nw; qx = nx; qy = ny; qz = nz;

        if (bodymask & (1ull << bid)) emit(bid);
    }
}

extern "C" void kernel_launch(void* const* d_in, const int* in_sizes, int n_in,
                              void* d_out, int out_size, void* d_ws, size_t ws_size,
                              hipStream_t stream)
{
    const float* qpos       = (const float*)d_in[0];
    const float* body_pos   = (const float*)d_in[1];
    const float* body_quat  = (const float*)d_in[2];
    const float* hinge_axis = (const float*)d_in[3];
    const float* jnt_pos    = (const float*)d_in[4];
    const float* site_pos   = (const float*)d_in[5];
    // d_in[6] = body_parent: max(arange-1,0) by construction -> serial chain, unused
    const int* site_body    = (const int*)d_in[7];
    float* ws = (float*)d_ws;

    int nb = in_sizes[0] / QDIM;   // 131072

    fk_setup<<<1, 64, 0, stream>>>(body_pos, body_quat, hinge_axis, jnt_pos,
                                   site_pos, site_body, ws);
    fk_main<<<(nb + 255) / 256, 256, 0, stream>>>(qpos, ws, (float*)d_out, nb);
}

// Round 5
// 131.345 us; speedup vs baseline: 1.0524x; 1.0524x over previous
//
#include <hip/hip_runtime.h>

// DifferentiableFK: serial 63-body hinge chain, B=131072, fp32 in/out.
// R4 passed at 48-57us: WRITE_SIZE 156MB vs 25MB ideal (6.2x amplification
// from 12B scattered-in-time site stores). R5: stage the 48 per-thread
// output floats in LDS (dynamic site index needs LDS, not regs), then one
// barrier + block-coalesced float4 copy-out -> full-line HBM writes.

#define NBODY  63
#define NHINGE 61
#define NSITES 16
#define QDIM   68   // 7 + NHINGE
#define LSTRIDE 49  // 48 floats/thread + 1 pad: lane*49 mod 32 = lane*17 -> 2-way only (free)

typedef unsigned int u32;

// ws float-index layout (setup kernel writes, main kernel reads)
#define HC_OFF   0                        // [61][16]: u.wxyz, v.wxyz, a.xyz+pad, j.xyz+pad
#define SP_OFF   (NHINGE * 16)            // 976: [16][4] site_pos
#define MASK_OFF (SP_OFF + NSITES * 4)    // 1040: int[63] per-body site bitmask
#define BM_OFF   (MASK_OFF + 64)          // 1104: 2 x u32 body bitmask

__global__ void fk_setup(const float* __restrict__ body_pos, const float* __restrict__ body_quat,
                         const float* __restrict__ hinge_axis, const float* __restrict__ jnt_pos,
                         const float* __restrict__ site_pos, const int* __restrict__ site_body,
                         float* __restrict__ ws)
{
    int tid = threadIdx.x;
    if (tid < NHINGE) {
        int h = tid, bid = h + 2;
        float uw = body_quat[bid*4+0], ux = body_quat[bid*4+1];
        float uy = body_quat[bid*4+2], uz = body_quat[bid*4+3];
        float ax = hinge_axis[h*3+0], ay = hinge_axis[h*3+1], az = hinge_axis[h*3+2];
        float jx = jnt_pos[h*3+0],   jy = jnt_pos[h*3+1],   jz = jnt_pos[h*3+2];
        float bx = body_pos[bid*3+0], by = body_pos[bid*3+1], bz = body_pos[bid*3+2];
        float* o = ws + HC_OFF + h * 16;
        o[0] = uw; o[1] = ux; o[2] = uy; o[3] = uz;
        // v = body_quat (x) (0, axis)  -> local = cos*u + sin*v
        o[4] = -(ux * ax + uy * ay + uz * az);
        o[5] =  uw * ax + uy * az - uz * ay;
        o[6] =  uw * ay - ux * az + uz * ax;
        o[7] =  uw * az + ux * ay - uy * ax;
        o[8] = bx + jx; o[9] = by + jy; o[10] = bz + jz; o[11] = 0.f;
        o[12] = jx; o[13] = jy; o[14] = jz; o[15] = 0.f;
    }
    if (tid < NSITES) {
        float* o = ws + SP_OFF + tid * 4;
        o[0] = site_pos[tid*3+0];
        o[1] = site_pos[tid*3+1];
        o[2] = site_pos[tid*3+2];
        o[3] = 0.f;
    }
    if (tid == 0) {
        int* im = (int*)(ws + MASK_OFF);
        unsigned long long bm = 0ull;
        for (int b = 0; b < NBODY; b++) {
            int m = 0;
            for (int s = 0; s < NSITES; s++)
                if (site_body[s] == b) m |= (1 << s);
            im[b] = m;
            if (m) bm |= (1ull << b);
        }
        u32* pbm = (u32*)(ws + BM_OFF);
        pbm[0] = (u32)bm; pbm[1] = (u32)(bm >> 32);
    }
}

__global__ __launch_bounds__(256, 2)
void fk_main(const float* __restrict__ qpos, const float* __restrict__ ws,
             float* __restrict__ out, int nb)
{
    __shared__ float sbuf[256 * LSTRIDE];   // 50176 B; 2 blocks/CU = 100 KB <= 160 KB
    const int tid = threadIdx.x;
    const int t = blockIdx.x * 256 + tid;
    float* my = sbuf + tid * LSTRIDE;

    if (t < nb) {
        // ---- load full qpos row: 68 floats = 272 B = 17 x float4 (16B-aligned) ----
        float f[QDIM];
        const float4* q4 = reinterpret_cast<const float4*>(qpos) + (size_t)t * 17;
#pragma unroll
        for (int i = 0; i < 17; i++) {
            float4 v = q4[i];
            f[4*i+0] = v.x; f[4*i+1] = v.y; f[4*i+2] = v.z; f[4*i+3] = v.w;
        }

        const u32* pbm = (const u32*)(ws + BM_OFF);
        unsigned long long bodymask = ((unsigned long long)pbm[1] << 32) | (unsigned long long)pbm[0];
        const int* im = (const int*)(ws + MASK_OFF);

        // ---- body 1: free joint ----
        float wpx = f[0], wpy = f[1], wpz = f[2];
        float qw = f[3], qx = f[4], qy = f[5], qz = f[6];
        float inv = rsqrtf(qw * qw + qx * qx + qy * qy + qz * qz);
        qw *= inv; qx *= inv; qy *= inv; qz *= inv;

        auto emit = [&](int bid) {
            int m = im[bid];          // wave-uniform
            while (m) {
                int s = __ffs(m) - 1; m &= m - 1;
                const float* sp = ws + SP_OFF + s * 4;
                float vx = sp[0], vy = sp[1], vz = sp[2];
                float tx = 2.f * (qy * vz - qz * vy);
                float ty = 2.f * (qz * vx - qx * vz);
                float tz = 2.f * (qx * vy - qy * vx);
                float* o = my + s * 3;               // LDS: dynamic s ok, 2-way bank max
                o[0] = wpx + vx + qw * tx + (qy * tz - qz * ty);
                o[1] = wpy + vy + qw * ty + (qz * tx - qx * tz);
                o[2] = wpz + vz + qw * tz + (qx * ty - qy * tx);
            }
        };

        if (bodymask & 2ull) emit(1);

        // ---- serial hinge chain, fully unrolled ----
#pragma unroll
        for (int h = 0; h < NHINGE; h++) {
            const int bid = h + 2;
            const float* c = ws + HC_OFF + h * 16;   // uniform, static offsets
            float ang = 0.5f * f[7 + h];
            float sn, cs;
            __sincosf(ang, &sn, &cs);
            // local = cs*u + sn*v
            float lw = cs * c[0] + sn * c[4];
            float lx = cs * c[1] + sn * c[5];
            float ly = cs * c[2] + sn * c[6];
            float lz = cs * c[3] + sn * c[7];
            // anchor = wp + qrot(wq, body_pos + jnt_pos)
            float ax = c[8], ay = c[9], az = c[10];
            float tx = 2.f * (qy * az - qz * ay);
            float ty = 2.f * (qz * ax - qx * az);
            float tz = 2.f * (qx * ay - qy * ax);
            float anx = wpx + ax + qw * tx + (qy * tz - qz * ty);
            float any_ = wpy + ay + qw * ty + (qz * tx - qx * tz);
            float anz = wpz + az + qw * tz + (qx * ty - qy * tx);
            // nq = qmul(wq, local)
            float nw = qw * lw - qx * lx - qy * ly - qz * lz;
            float nx = qw * lx + qx * lw + qy * lz - qz * ly;
            float ny = qw * ly - qx * lz + qy * lw + qz * lx;
            float nz = qw * lz + qx * ly - qy * lx + qz * lw;
            // wp = anchor - qrot(nq, jnt_pos)
            float jx = c[12], jy = c[13], jz = c[14];
            float t2x = 2.f * (ny * jz - nz * jy);
            float t2y = 2.f * (nz * jx - nx * jz);
            float t2z = 2.f * (nx * jy - ny * jx);
            wpx = anx - (jx + nw * t2x + (ny * t2z - nz * t2y));
            wpy = any_ - (jy + nw * t2y + (nz * t2x - nx * t2z));
            wpz = anz - (jz + nw * t2z + (nx * t2y - ny * t2x));
            qw = nw; qx = nx; qy = ny; qz = nz;

            if (bodymask & (1ull << bid)) emit(bid);
        }
    }

    __syncthreads();

    // ---- coalesced copy-out: block region = 256 threads * 48 floats = 48 KiB ----
    // float4 g (lane-consecutive): thread q = g/12, dword offs r = 4*(g%12);
    // each float4 stays inside one thread's 48-float region (48 % 4 == 0).
    {
        size_t blk_dw = (size_t)blockIdx.x * (256 * 48);
        if (blk_dw + 256 * 48 <= (size_t)nb * 48) {
            float4* out4 = reinterpret_cast<float4*>(out + blk_dw);
#pragma unroll
            for (int k = 0; k < 12; k++) {
                int g = k * 256 + tid;
                int q = g / 12;
                int r = (g - q * 12) * 4;
                const float* p = sbuf + q * LSTRIDE + r;
                float4 v = { p[0], p[1], p[2], p[3] };
                out4[g] = v;   // 64 lanes x 16B contiguous = 1 KiB/instr
            }
        }
    }
}

extern "C" void kernel_launch(void* const* d_in, const int* in_sizes, int n_in,
                              void* d_out, int out_size, void* d_ws, size_t ws_size,
                              hipStream_t stream)
{
    const float* qpos       = (const float*)d_in[0];
    const float* body_pos   = (const float*)d_in[1];
    const float* body_quat  = (const float*)d_in[2];
    const float* hinge_axis = (const float*)d_in[3];
    const float* jnt_pos    = (const float*)d_in[4];
    const float* site_pos   = (const float*)d_in[5];
    // d_in[6] = body_parent: max(arange-1,0) by construction -> serial chain, unused
    const int* site_body    = (const int*)d_in[7];
    float* ws = (float*)d_ws;

    int nb = in_sizes[0] / QDIM;   // 131072

    fk_setup<<<1, 64, 0, stream>>>(body_pos, body_quat, hinge_axis, jnt_pos,
                                   site_pos, site_body, ws);
    fk_main<<<(nb + 255) / 256, 256, 0, stream>>>(qpos, ws, (float*)d_out, nb);
}